// Round 2
// baseline (193.428 us; speedup 1.0000x reference)
//
#include <hip/hip_runtime.h>
#include <stdint.h>

typedef unsigned short u16;
typedef __attribute__((ext_vector_type(8))) short short8;
typedef __attribute__((ext_vector_type(4))) float f32x4;

#define NDIM 256
#define SDIM 128
#define DDIM 64
#define HDIM 32
#define PDIM 64
#define EPS 1e-5f

// k_fused tiling: block tile 256m(i:8) x 128n(j:4), 512 threads = 8 waves (4 wm x 2 wn)
#define IB 8
#define JB 4

__device__ __forceinline__ u16 f2bf(float f) {
  union { float f; uint32_t u; } v; v.f = f;
  uint32_t r = v.u + 0x7fffu + ((v.u >> 16) & 1u);   // RNE
  return (u16)(r >> 16);
}

// ---------------- K1: LN + dual projection, wave-per-row ----------------
// grid 512: block = (n = bid>>1, sh = bid&1 covering s in [sh*64, sh*64+64)).
// 256 threads = 4 waves; wave wv handles 16 rows. Lane d=0..63 per row for LN;
// then lane -> (proj = lane>>5, h = lane&31), W held in 64 regs, shfl-broadcast x.
__global__ __launch_bounds__(256, 4) void k_pre(
    const float* __restrict__ msa, const float* __restrict__ mask,
    const float* __restrict__ gamma, const float* __restrict__ beta,
    const float* __restrict__ Wa, const float* __restrict__ ba,
    const float* __restrict__ Wb, const float* __restrict__ bb,
    const float* __restrict__ Wo, const float* __restrict__ bo_unused,
    u16* __restrict__ a_t, u16* __restrict__ b_t, u16* __restrict__ W_t)
{
  __shared__ float Wl[2][64][32];   // 16KB  [proj][d][h]
  __shared__ float gbL[128];        // gamma | beta
  __shared__ float maskL[128];
  __shared__ u16 aTl[64 * 64];      // [s_local][c = proj*32+h]  8KB

  const int n  = blockIdx.x >> 1;
  const int sh = blockIdx.x & 1;
  const int t = threadIdx.x, lane = t & 63, wv = t >> 6;

  #pragma unroll
  for (int i = 0; i < 4; ++i) {
    const int f = i * 256 + t;        // 1024 float4 = 4096 floats
    const float4 v = (f < 512) ? ((const float4*)Wa)[f] : ((const float4*)Wb)[f - 512];
    ((float4*)Wl)[f] = v;
  }
  if (t < 64) gbL[t] = gamma[t];
  else if (t < 128) gbL[t] = beta[t - 64];
  if (t < 128) maskL[t] = mask[t * NDIM + n];
  __syncthreads();

  float dsum = 0.f;
  for (int ss = 0; ss < 128; ++ss) dsum += maskL[ss];
  const float dinv = 1.f / fmaxf(dsum, 1.f);

  const int proj = lane >> 5, h = lane & 31;
  float wreg[64];
  #pragma unroll
  for (int d = 0; d < 64; ++d) wreg[d] = Wl[proj][d][h];
  const float bias = proj ? bb[h] : ba[h];
  const float gam = gbL[lane], bet = gbL[64 + lane];

  for (int r = 0; r < 16; ++r) {
    const int sl = wv * 16 + r;          // 0..63
    const int s = sh * 64 + sl;
    const float x = msa[(s * NDIM + n) * DDIM + lane];   // coalesced 256B
    float sum = x;
    #pragma unroll
    for (int m = 32; m; m >>= 1) sum += __shfl_xor(sum, m, 64);
    const float mu = sum * (1.f / 64.f);
    const float df = x - mu;
    float vs = df * df;
    #pragma unroll
    for (int m = 32; m; m >>= 1) vs += __shfl_xor(vs, m, 64);
    const float xn = df * rsqrtf(vs * (1.f / 64.f) + EPS) * gam + bet;
    float acc = bias;
    #pragma unroll
    for (int d = 0; d < 64; ++d) acc = fmaf(__shfl(xn, d, 64), wreg[d], acc);
    const float mval = maskL[s];
    const float scale = proj ? mval : mval * dinv;   // 1/denom folded into a
    aTl[sl * 64 + lane] = f2bf(acc * scale);
  }
  __syncthreads();

  // dump: wave wv handles s-block [wv*16, +16), c = lane
  {
    const int c = lane;                  // proj*32+h
    short8 v0, v1;
    #pragma unroll
    for (int k = 0; k < 8; ++k)  v0[k] = (short)aTl[(wv * 16 + k) * 64 + c];
    #pragma unroll
    for (int k = 0; k < 8; ++k)  v1[k] = (short)aTl[(wv * 16 + 8 + k) * 64 + c];
    u16* dst = (c < 32 ? a_t : b_t) + n * 4096 + (c & 31) * 128 + sh * 64 + wv * 16;
    *(short8*)dst = v0;
    *(short8*)(dst + 8) = v1;
  }
  // W_t[p][hk] = bf16(Wo[hk][p]) : first 256 blocks cover 65536 elems
  if (blockIdx.x < 256) {
    const int f = blockIdx.x * 256 + t;
    const int p = f >> 10, hk = f & 1023;
    W_t[f] = f2bf(Wo[hk * 64 + p]);
  }
}

// ---------------- K2: fused outer-product GEMM + Wo contraction ----------------
// grid (64 jT, 32 iT) x 512 thr. Stage A: G[256x128] over K=128 (2 chunks of 64),
// A-frags direct from global (a_t K-major), B staged in swizzled LDS (16KB chunk,
// aliased into Gs). Gs: 32 rij x 1024 hk bf16, XOR-swizzled granules (64KB).
// Stage B: wave = (pt = wv&3, kh = wv>>2): out[32 rij][16p] over K-half, pairwise
// LDS reduce, +bo, store.
__global__ __launch_bounds__(512, 4) void k_fused(
    const u16* __restrict__ a_t, const u16* __restrict__ b_t,
    const u16* __restrict__ W_t, const float* __restrict__ bo,
    float* __restrict__ out)
{
  __shared__ char smem[65536];
  u16* Bs = (u16*)smem;          // [128 rows][64 k] swizzled granules, 16KB (stage A only)
  u16* Gs = (u16*)smem;          // [32 rij][1024 hk] swizzled, 64KB (after stage A)

  const int tid = threadIdx.x;
  const int lane = tid & 63;
  const int wv = tid >> 6;           // 0..7
  const int l15 = lane & 15;
  const int quad = lane >> 4;        // 0..3
  const int wm = wv >> 1, wn = wv & 1;
  const int jT = blockIdx.x, iT = blockIdx.y;

  const u16* gA = a_t + iT * 256 * SDIM;
  const u16* gB = b_t + jT * 128 * SDIM;

  const f32x4 fz = {0.f, 0.f, 0.f, 0.f};
  f32x4 acc[4][4];
  #pragma unroll
  for (int mt = 0; mt < 4; ++mt)
    #pragma unroll
    for (int nt = 0; nt < 4; ++nt) acc[mt][nt] = fz;

  for (int ch = 0; ch < 2; ++ch) {
    __syncthreads();
    #pragma unroll
    for (int it = 0; it < 2; ++it) {            // 1024 granules of 8 u16
      const int flat = it * 512 + tid;
      const int row = flat >> 3, g = flat & 7;
      *(short8*)&Bs[row * 64 + ((g ^ (row & 7)) << 3)] =
          *(const short8*)&gB[row * SDIM + ch * 64 + (g << 3)];
    }
    __syncthreads();
    #pragma unroll
    for (int ks = 0; ks < 2; ++ks) {
      const int kglob = ch * 64 + ks * 32 + quad * 8;
      short8 af[4], bf[4];
      #pragma unroll
      for (int mt = 0; mt < 4; ++mt)
        af[mt] = *(const short8*)&gA[(wm * 64 + mt * 16 + l15) * SDIM + kglob];
      #pragma unroll
      for (int nt = 0; nt < 4; ++nt) {
        const int r = wn * 64 + nt * 16 + l15;
        const int gk = ks * 4 + quad;
        bf[nt] = *(const short8*)&Bs[r * 64 + ((gk ^ (r & 7)) << 3)];
      }
      #pragma unroll
      for (int mt = 0; mt < 4; ++mt)
        #pragma unroll
        for (int nt = 0; nt < 4; ++nt)
          acc[mt][nt] = __builtin_amdgcn_mfma_f32_16x16x32_bf16(af[mt], bf[nt], acc[mt][nt], 0, 0, 0);
    }
  }
  __syncthreads();   // all Bs reads done; Gs (aliases Bs) safe to write

  // Gs dump: C/D 16x16 layout row=quad*4+reg, col=l15.
  // slot = (hi<<3) | (g^rij^hi)&7 : conflict-free across quad & granule.
  #pragma unroll
  for (int mt = 0; mt < 4; ++mt)
    #pragma unroll
    for (int nt = 0; nt < 4; ++nt) {
      const int rij = (2 * wm + (mt >> 1)) * 4 + 2 * wn + (nt >> 1);
      const int n31 = (nt & 1) * 16 + l15;
      #pragma unroll
      for (int r = 0; r < 4; ++r) {
        const int m31 = (mt & 1) * 16 + quad * 4 + r;
        const int hk = m31 * 32 + n31;
        const int g = hk >> 3, hi = g >> 3;
        const int slot = (hi << 3) | ((g ^ rij ^ hi) & 7);
        Gs[rij * 1024 + slot * 8 + (hk & 7)] = f2bf(acc[mt][nt][r]);
      }
    }
  __syncthreads();

  // Stage B: wave (pt, kh): rows rij l15 & 16+l15, p-tile pt, K-half kh.
  const int pt = wv & 3, kh = wv >> 2;
  const int p = pt * 16 + l15;
  f32x4 ob0 = fz, ob1 = fz;
  const u16* wbase = W_t + p * 1024;
  const int r0 = l15, r1 = 16 + l15;
  #pragma unroll
  for (int kk = kh * 16; kk < kh * 16 + 16; ++kk) {
    const short8 wf = *(const short8*)&wbase[kk * 32 + quad * 8];
    const int g = kk * 4 + quad, hi = g >> 3;
    const short8 g0 = *(const short8*)&Gs[r0 * 1024 + (((hi << 3) | ((g ^ r0 ^ hi) & 7)) << 3)];
    const short8 g1 = *(const short8*)&Gs[r1 * 1024 + (((hi << 3) | ((g ^ r1 ^ hi) & 7)) << 3)];
    ob0 = __builtin_amdgcn_mfma_f32_16x16x32_bf16(g0, wf, ob0, 0, 0, 0);
    ob1 = __builtin_amdgcn_mfma_f32_16x16x32_bf16(g1, wf, ob1, 0, 0, 0);
  }
  __syncthreads();   // all Gs reads done; reuse smem as reduce buffer

  float* red = (float*)smem;   // [pt][mh][row 16 x pitch 20] = 2560 f32 = 10KB
  if (kh) {
    #pragma unroll
    for (int r = 0; r < 4; ++r) {
      red[pt * 640 +       (quad * 4 + r) * 20 + l15] = ob0[r];
      red[pt * 640 + 320 + (quad * 4 + r) * 20 + l15] = ob1[r];
    }
  }
  __syncthreads();
  if (!kh) {
    const float bop = bo[p];
    #pragma unroll
    for (int r = 0; r < 4; ++r) {
      const float v0 = ob0[r] + red[pt * 640 +       (quad * 4 + r) * 20 + l15] + bop;
      const float v1 = ob1[r] + red[pt * 640 + 320 + (quad * 4 + r) * 20 + l15] + bop;
      const int rij0 = quad * 4 + r;
      const int rij1 = 16 + quad * 4 + r;
      {
        const int iG = iT * IB + (rij0 >> 2), jG = jT * JB + (rij0 & 3);
        out[(iG * NDIM + jG) * PDIM + p] = v0;
      }
      {
        const int iG = iT * IB + (rij1 >> 2), jG = jT * JB + (rij1 & 3);
        out[(iG * NDIM + jG) * PDIM + p] = v1;
      }
    }
  }
}

extern "C" void kernel_launch(void* const* d_in, const int* in_sizes, int n_in,
                              void* d_out, int out_size, void* d_ws, size_t ws_size,
                              hipStream_t stream) {
  const float* msa   = (const float*)d_in[0];
  const float* mask  = (const float*)d_in[1];
  const float* gamma = (const float*)d_in[2];
  const float* beta  = (const float*)d_in[3];
  const float* Wa    = (const float*)d_in[4];
  const float* ba    = (const float*)d_in[5];
  const float* Wb    = (const float*)d_in[6];
  const float* bb    = (const float*)d_in[7];
  const float* Wo    = (const float*)d_in[8];
  const float* bo    = (const float*)d_in[9];

  char* ws = (char*)d_ws;
  u16* a_t = (u16*)ws;                       // 2 MB: [8192 ih][128 s] bf16
  u16* b_t = (u16*)(ws + (2u << 20));        // 2 MB: [8192 jk][128 s] bf16
  u16* W_t = (u16*)(ws + (4u << 20));        // 128 KB: [64 p][1024 hk] bf16

  k_pre<<<dim3(512), dim3(256), 0, stream>>>(msa, mask, gamma, beta,
                                             Wa, ba, Wb, bb, Wo, bo, a_t, b_t, W_t);
  k_fused<<<dim3(64, 32), dim3(512), 0, stream>>>(a_t, b_t, W_t, bo, (float*)d_out);
}

// Round 3
// 148.151 us; speedup vs baseline: 1.3056x; 1.3056x over previous
//
#include <hip/hip_runtime.h>
#include <hip/hip_bf16.h>
#include <stdint.h>

typedef unsigned short u16;
typedef __attribute__((ext_vector_type(8))) short short8;
typedef __attribute__((ext_vector_type(4))) float f32x4;

#define NDIM 256
#define SDIM 128
#define DDIM 64
#define HDIM 32
#define PDIM 64
#define EPS 1e-5f

__device__ __forceinline__ u16 f2bf(float f) {
  union { float f; uint32_t u; } v; v.f = f;
  uint32_t r = v.u + 0x7fffu + ((v.u >> 16) & 1u);   // RNE
  return (u16)(r >> 16);
}
__device__ __forceinline__ uint32_t pk2(float a, float b) {
  __hip_bfloat162 h = __float22bfloat162_rn(float2{a, b});   // HW pk-cvt on gfx950
  union { __hip_bfloat162 h; uint32_t u; } c; c.h = h;
  return c.u;
}

// ---------------- K1: LN + dual projection ----------------
// grid 256 (block per n), 256 threads: thread = (s = t&127, proj = t>>7).
// x-rows + W + gamma/beta + mask staged in LDS once; per-thread independent
// fma chains; W reads are wave-broadcast (proj,d uniform per wave).
__global__ __launch_bounds__(256) void k_pre(
    const float* __restrict__ msa, const float* __restrict__ mask,
    const float* __restrict__ gamma, const float* __restrict__ beta,
    const float* __restrict__ Wa, const float* __restrict__ ba,
    const float* __restrict__ Wb, const float* __restrict__ bb,
    const float* __restrict__ Wo,
    u16* __restrict__ a_t, u16* __restrict__ b_t, u16* __restrict__ W_t)
{
  __shared__ float xL[128 * 68];     // pitch 68: 16B-aligned rows, 4-bank row phase
  __shared__ float Wl[2][64][32];    // 16KB
  __shared__ float gbL[128];
  __shared__ float maskL[128];

  const int n = blockIdx.x;
  const int t = threadIdx.x;

  #pragma unroll
  for (int it = 0; it < 8; ++it) {                 // 2048 float4 = 128 rows x 64 d
    const int f = it * 256 + t;
    const int row = f >> 4, c = f & 15;
    const float4 v = *(const float4*)&msa[(row * NDIM + n) * DDIM + c * 4];
    *(float4*)&xL[row * 68 + c * 4] = v;
  }
  #pragma unroll
  for (int it = 0; it < 4; ++it) {                 // 1024 float4 = Wa|Wb
    const int f = it * 256 + t;
    const float4 v = (f < 512) ? ((const float4*)Wa)[f] : ((const float4*)Wb)[f - 512];
    ((float4*)Wl)[f] = v;
  }
  if (t < 64) gbL[t] = gamma[t];
  else if (t < 128) gbL[t] = beta[t - 64];
  if (t < 128) maskL[t] = mask[t * NDIM + n];
  __syncthreads();

  const int s = t & 127, proj = t >> 7;            // proj uniform per wave

  float dsum = 0.f;
  for (int ss = 0; ss < 128; ++ss) dsum += maskL[ss];   // broadcast reads
  const float dinv = 1.f / fmaxf(dsum, 1.f);

  float x[64];
  float sum = 0.f;
  #pragma unroll
  for (int j = 0; j < 16; ++j) {
    const float4 v = *(const float4*)&xL[s * 68 + j * 4];
    x[4*j] = v.x; x[4*j+1] = v.y; x[4*j+2] = v.z; x[4*j+3] = v.w;
    sum += v.x + v.y + v.z + v.w;
  }
  const float mu = sum * (1.f / 64.f);
  float vs = 0.f;
  #pragma unroll
  for (int d = 0; d < 64; ++d) { const float df = x[d] - mu; vs += df * df; }
  const float rs = rsqrtf(vs * (1.f / 64.f) + EPS);
  #pragma unroll
  for (int d = 0; d < 64; ++d)
    x[d] = (x[d] - mu) * rs * gbL[d] + gbL[64 + d];

  float acc[32];
  const float* bsel = proj ? bb : ba;
  #pragma unroll
  for (int h = 0; h < 32; ++h) acc[h] = bsel[h];
  #pragma unroll 2
  for (int d = 0; d < 64; ++d) {
    const float xv = x[d];
    #pragma unroll
    for (int h4 = 0; h4 < 8; ++h4) {
      const float4 w = *(const float4*)&Wl[proj][d][h4 * 4];   // broadcast
      acc[h4*4+0] = fmaf(xv, w.x, acc[h4*4+0]);
      acc[h4*4+1] = fmaf(xv, w.y, acc[h4*4+1]);
      acc[h4*4+2] = fmaf(xv, w.z, acc[h4*4+2]);
      acc[h4*4+3] = fmaf(xv, w.w, acc[h4*4+3]);
    }
  }
  const float mval = maskL[s];
  const float scale = proj ? mval : mval * dinv;   // 1/denom folded into a
  u16* dst = (proj ? b_t : a_t) + n * 4096 + s;    // lane = s -> 128B coalesced per h
  #pragma unroll
  for (int h = 0; h < 32; ++h) dst[h * 128] = f2bf(acc[h] * scale);

  // W_t[p*1024 + hk] = bf16(Wo[hk*64 + p])
  {
    const int f = blockIdx.x * 256 + t;
    const int p = f >> 10, hk = f & 1023;
    W_t[f] = f2bf(Wo[hk * 64 + p]);
  }
}

// ---------------- K2: fused outer-product GEMM + Wo contraction ----------------
// grid (64 jT, 32 iT) x 256 thr (4 waves, 2x2: wm=ih-half, wn=jk-half).
// Stage A (swapped operands): D[m=jk, n=ih] so C-frag regs = 4 consecutive hk
// -> packed b64 dump into swizzled Gs. Stage B: wave = p-tile, rows l15/16+l15,
// K=1024, reads Gs (swizzle inverted) + W_t from L2.
__global__ __launch_bounds__(256, 2) void k_fused(
    const u16* __restrict__ a_t, const u16* __restrict__ b_t,
    const u16* __restrict__ W_t, const float* __restrict__ bo,
    float* __restrict__ out)
{
  __shared__ char smem[65536];
  u16* As = (u16*)smem;              // [256 ih][64 k] swizzled granules, 32KB
  u16* Bs = (u16*)(smem + 32768);    // [128 jk][64 k] swizzled granules, 16KB
  u16* Gs = (u16*)smem;              // [32 rij][1024 hk] swizzled, 64KB (after stage A)

  const int tid = threadIdx.x, lane = tid & 63, wv = tid >> 6;
  const int l15 = lane & 15, quad = lane >> 4;
  const int wm = wv >> 1, wn = wv & 1;
  const int jT = blockIdx.x, iT = blockIdx.y;

  const u16* gA = a_t + iT * 256 * SDIM;
  const u16* gB = b_t + jT * 128 * SDIM;

  const f32x4 fz = {0.f, 0.f, 0.f, 0.f};
  f32x4 acc[4][8];                   // [jt][it]
  #pragma unroll
  for (int jt = 0; jt < 4; ++jt)
    #pragma unroll
    for (int it = 0; it < 8; ++it) acc[jt][it] = fz;

  for (int ch = 0; ch < 2; ++ch) {
    __syncthreads();
    #pragma unroll
    for (int it = 0; it < 8; ++it) {             // As: 2048 granules
      const int f = it * 256 + tid;
      const int row = f >> 3, g = f & 7;
      *(short8*)&As[row * 64 + ((g ^ (row & 7)) << 3)] =
          *(const short8*)&gA[row * SDIM + ch * 64 + (g << 3)];
    }
    #pragma unroll
    for (int it = 0; it < 4; ++it) {             // Bs: 1024 granules
      const int f = it * 256 + tid;
      const int row = f >> 3, g = f & 7;
      *(short8*)&Bs[row * 64 + ((g ^ (row & 7)) << 3)] =
          *(const short8*)&gB[row * SDIM + ch * 64 + (g << 3)];
    }
    __syncthreads();
    #pragma unroll
    for (int ks = 0; ks < 2; ++ks) {
      const int g = ks * 4 + quad;
      short8 af[8], bf[4];
      #pragma unroll
      for (int it = 0; it < 8; ++it) {
        const int row = wm * 128 + it * 16 + l15;
        af[it] = *(const short8*)&As[row * 64 + ((g ^ (row & 7)) << 3)];
      }
      #pragma unroll
      for (int jt = 0; jt < 4; ++jt) {
        const int row = wn * 64 + jt * 16 + l15;
        bf[jt] = *(const short8*)&Bs[row * 64 + ((g ^ (row & 7)) << 3)];
      }
      #pragma unroll
      for (int jt = 0; jt < 4; ++jt)
        #pragma unroll
        for (int it = 0; it < 8; ++it)
          acc[jt][it] = __builtin_amdgcn_mfma_f32_16x16x32_bf16(bf[jt], af[it], acc[jt][it], 0, 0, 0);
    }
  }
  __syncthreads();

  // Gs dump: D[m=jk (quad*4+r), n=ih (l15)]; 4 regs = 4 consecutive hk -> b64.
  // Swizzle S(g4,rij) = g4 ^ ((g4>>4)&6) ^ ((rij&7)<<1)  (bit0 preserved).
  #pragma unroll
  for (int jt = 0; jt < 4; ++jt)
    #pragma unroll
    for (int it = 0; it < 8; ++it) {
      const int rij = (wm * 4 + (it >> 1)) * 4 + (wn * 2 + (jt >> 1));
      const int ih31 = (it & 1) * 16 + l15;
      const int hk = ih31 * 32 + (jt & 1) * 16 + quad * 4;   // base of 4
      const int g4 = hk >> 2;
      const int g4s = g4 ^ ((g4 >> 4) & 6) ^ ((rij & 7) << 1);
      uint32_t lo = pk2(acc[jt][it][0], acc[jt][it][1]);
      uint32_t hi = pk2(acc[jt][it][2], acc[jt][it][3]);
      uint2 pk; pk.x = lo; pk.y = hi;
      *(uint2*)&Gs[rij * 1024 + (g4s << 2)] = pk;
    }
  __syncthreads();

  // Stage B: wave wv = p-tile; rows r0=l15, r1=16+l15; kk = 0..31 over K=1024.
  f32x4 ob0 = fz, ob1 = fz;
  const u16* wbase = W_t + (wv * 16 + l15) * 1024;
  const int r0 = l15, r1 = 16 + l15;
  #pragma unroll 4
  for (int kk = 0; kk < 32; ++kk) {
    const short8 wf = *(const short8*)&wbase[kk * 32 + quad * 8];
    const int g4e = kk * 8 + quad * 2;
    const int go = (g4e ^ ((g4e >> 4) & 6) ^ ((l15 & 7) << 1)) << 2;   // same for r0,r1
    const short8 g0 = *(const short8*)&Gs[r0 * 1024 + go];
    const short8 g1 = *(const short8*)&Gs[r1 * 1024 + go];
    ob0 = __builtin_amdgcn_mfma_f32_16x16x32_bf16(g0, wf, ob0, 0, 0, 0);
    ob1 = __builtin_amdgcn_mfma_f32_16x16x32_bf16(g1, wf, ob1, 0, 0, 0);
  }
  const int p = wv * 16 + l15;
  const float bop = bo[p];
  #pragma unroll
  for (int r = 0; r < 4; ++r) {
    {
      const int rij = quad * 4 + r;
      const int iG = iT * 8 + (rij >> 2), jG = jT * 4 + (rij & 3);
      out[(iG * NDIM + jG) * PDIM + p] = ob0[r] + bop;
    }
    {
      const int rij = 16 + quad * 4 + r;
      const int iG = iT * 8 + (rij >> 2), jG = jT * 4 + (rij & 3);
      out[(iG * NDIM + jG) * PDIM + p] = ob1[r] + bop;
    }
  }
}

extern "C" void kernel_launch(void* const* d_in, const int* in_sizes, int n_in,
                              void* d_out, int out_size, void* d_ws, size_t ws_size,
                              hipStream_t stream) {
  const float* msa   = (const float*)d_in[0];
  const float* mask  = (const float*)d_in[1];
  const float* gamma = (const float*)d_in[2];
  const float* beta  = (const float*)d_in[3];
  const float* Wa    = (const float*)d_in[4];
  const float* ba    = (const float*)d_in[5];
  const float* Wb    = (const float*)d_in[6];
  const float* bb    = (const float*)d_in[7];
  const float* Wo    = (const float*)d_in[8];
  const float* bo    = (const float*)d_in[9];

  char* ws = (char*)d_ws;
  u16* a_t = (u16*)ws;                       // 2 MB: [8192 ih][128 s] bf16
  u16* b_t = (u16*)(ws + (2u << 20));        // 2 MB: [8192 jk][128 s] bf16
  u16* W_t = (u16*)(ws + (4u << 20));        // 128 KB: [64 p][1024 hk] bf16

  k_pre<<<dim3(256), dim3(256), 0, stream>>>(msa, mask, gamma, beta,
                                             Wa, ba, Wb, bb, Wo, a_t, b_t, W_t);
  k_fused<<<dim3(64, 32), dim3(256), 0, stream>>>(a_t, b_t, W_t, bo, (float*)d_out);
}

// Round 4
// 130.645 us; speedup vs baseline: 1.4806x; 1.1340x over previous
//
#include <hip/hip_runtime.h>
#include <hip/hip_bf16.h>
#include <stdint.h>

typedef unsigned short u16;
typedef __attribute__((ext_vector_type(8))) short short8;
typedef __attribute__((ext_vector_type(4))) float f32x4;

#define NDIM 256
#define SDIM 128
#define DDIM 64
#define HDIM 32
#define PDIM 64
#define EPS 1e-5f

__device__ __forceinline__ u16 f2bf(float f) {
  union { float f; uint32_t u; } v; v.f = f;
  uint32_t r = v.u + 0x7fffu + ((v.u >> 16) & 1u);   // RNE
  return (u16)(r >> 16);
}

// ---------------- K1: LN + dual projection via MFMA ----------------
// grid 512: block = (n = bid>>1, sh = bid&1 -> s in [sh*64, sh*64+64)).
// 256 thr = 4 waves. Thread (sl = lane, part = wv) does LN for row sl,
// d-slice part*16..+16 (16 floats/thread -> NO spills). X_norm and W^T staged
// in LDS bf16 (XOR-swizzled granules); projection = MFMA D[m=c][n=s],
// wave wv = c-tile. Epilogue: +bias, *mask (*dinv for a), store to a_t/b_t.
__global__ __launch_bounds__(256, 4) void k_pre(
    const float* __restrict__ msa, const float* __restrict__ mask,
    const float* __restrict__ gamma, const float* __restrict__ beta,
    const float* __restrict__ Wa, const float* __restrict__ ba,
    const float* __restrict__ Wb, const float* __restrict__ bb,
    const float* __restrict__ Wo,
    u16* __restrict__ a_t, u16* __restrict__ b_t, u16* __restrict__ W_t)
{
  __shared__ u16 xs[64 * 64];        // [sl][slot*8] swizzled, 8KB: X_norm bf16
  __shared__ u16 wt[64 * 64];        // [c][slot*8]  swizzled, 8KB: W^T bf16 ([Wa|Wb] cols)
  __shared__ float psum[2][4][64];   // LN partial sums
  __shared__ float maskF[128];
  __shared__ float gbF[128];         // gamma | beta

  const int n = blockIdx.x >> 1, sh = blockIdx.x & 1;
  const int t = threadIdx.x, lane = t & 63, wv = t >> 6;
  const int l15 = lane & 15, quad = lane >> 4;
  const int sl = lane, part = wv;

  if (t < 64) gbF[t] = gamma[t];
  else if (t < 128) gbF[t] = beta[t - 64];
  else maskF[t - 128] = mask[(t - 128) * NDIM + n];

  // msa slice: row s = sh*64+sl, d = part*16..+16
  const int s_row = sh * 64 + sl;
  float x[16];
  {
    const float* xr = msa + (s_row * NDIM + n) * DDIM + part * 16;
    float sum = 0.f, sq = 0.f;
    #pragma unroll
    for (int i = 0; i < 4; ++i) {
      const float4 q = ((const float4*)xr)[i];
      x[4*i] = q.x; x[4*i+1] = q.y; x[4*i+2] = q.z; x[4*i+3] = q.w;
      sum += q.x + q.y + q.z + q.w;
      sq += q.x*q.x + q.y*q.y + q.z*q.z + q.w*q.w;
    }
    psum[0][part][sl] = sum;
    psum[1][part][sl] = sq;
  }

  // W^T: c = sl (c<32 -> Wa col, else Wb col), d-slice part*16..+16
  {
    const int c31 = sl & 31;
    const float* Wsel = (sl >> 5) ? Wb : Wa;
    float w[16];
    #pragma unroll
    for (int i = 0; i < 16; ++i) w[i] = Wsel[(part * 16 + i) * HDIM + c31];
    #pragma unroll
    for (int jj = 0; jj < 2; ++jj) {
      short8 v;
      #pragma unroll
      for (int k = 0; k < 8; ++k) v[k] = (short)f2bf(w[jj * 8 + k]);
      *(short8*)&wt[sl * 64 + (((part * 2 + jj) ^ (sl & 7)) << 3)] = v;
    }
  }
  __syncthreads();

  // finish LN for row sl
  {
    const float s0 = psum[0][0][sl] + psum[0][1][sl] + psum[0][2][sl] + psum[0][3][sl];
    const float s1 = psum[1][0][sl] + psum[1][1][sl] + psum[1][2][sl] + psum[1][3][sl];
    const float mu = s0 * (1.f / 64.f);
    const float var = s1 * (1.f / 64.f) - mu * mu;
    const float rs = rsqrtf(var + EPS);
    #pragma unroll
    for (int jj = 0; jj < 2; ++jj) {
      short8 v;
      #pragma unroll
      for (int k = 0; k < 8; ++k) {
        const int d = part * 16 + jj * 8 + k;
        v[k] = (short)f2bf((x[jj * 8 + k] - mu) * rs * gbF[d] + gbF[64 + d]);
      }
      *(short8*)&xs[sl * 64 + (((part * 2 + jj) ^ (sl & 7)) << 3)] = v;
    }
  }
  float dsum = 0.f;
  for (int ss = 0; ss < 128; ++ss) dsum += maskF[ss];   // broadcast reads
  const float dinv = 1.f / fmaxf(dsum, 1.f);
  __syncthreads();

  // projection MFMA: D[m=c][n=s], wave wv owns c-tile [wv*16, +16)
  const f32x4 fz = {0.f, 0.f, 0.f, 0.f};
  f32x4 acc[4];
  #pragma unroll
  for (int nt = 0; nt < 4; ++nt) acc[nt] = fz;
  short8 af[2];
  #pragma unroll
  for (int ks = 0; ks < 2; ++ks)
    af[ks] = *(const short8*)&wt[(wv * 16 + l15) * 64 + (((ks * 4 + quad) ^ (l15 & 7)) << 3)];
  #pragma unroll
  for (int nt = 0; nt < 4; ++nt)
    #pragma unroll
    for (int ks = 0; ks < 2; ++ks) {
      const short8 bf = *(const short8*)&xs[(nt * 16 + l15) * 64 + (((ks * 4 + quad) ^ (l15 & 7)) << 3)];
      acc[nt] = __builtin_amdgcn_mfma_f32_16x16x32_bf16(af[ks], bf, acc[nt], 0, 0, 0);
    }

  // epilogue: +bias, scale, store. wave 0,1 -> a_t rows 0..31; wave 2,3 -> b_t.
  const float* bsel = (wv < 2) ? ba : bb;
  float bias_r[4];
  #pragma unroll
  for (int r = 0; r < 4; ++r) bias_r[r] = bsel[(wv & 1) * 16 + quad * 4 + r];
  u16* dstbase = ((wv < 2) ? a_t : b_t) + n * 4096;
  #pragma unroll
  for (int nt = 0; nt < 4; ++nt) {
    const int s = sh * 64 + nt * 16 + l15;
    const float mval = maskF[s];
    const float scale = (wv < 2) ? mval * dinv : mval;   // 1/denom folded into a
    #pragma unroll
    for (int r = 0; r < 4; ++r) {
      const int c31 = (wv & 1) * 16 + quad * 4 + r;
      dstbase[c31 * 128 + s] = f2bf((acc[nt][r] + bias_r[r]) * scale);
    }
  }

  // W_t[p*1024 + hk] = bf16(Wo[hk*64 + p])
  if (blockIdx.x < 256) {
    const int f = blockIdx.x * 256 + t;
    const int p = f >> 10, hk = f & 1023;
    W_t[f] = f2bf(Wo[hk * 64 + p]);
  }
}

// ---------------- K2: fused outer-product GEMM + Wo contraction ----------------
// grid (64 jT, 32 iT) x 256 thr (4 waves). Stage A: G-tile 256ih x 128jk over
// K=128, swapped operands (D[m=jk][n=ih]) -> packed b64 dump into swizzled Gs.
// Stage B: waves split K (each wave owns a 256-wide hk quarter, reads its Gs
// slice exactly once), then padded-pitch LDS partial exchange + store.
__global__ __launch_bounds__(256, 2) void k_fused(
    const u16* __restrict__ a_t, const u16* __restrict__ b_t,
    const u16* __restrict__ W_t, const float* __restrict__ bo,
    float* __restrict__ out)
{
  __shared__ char smem[65536];
  u16* As = (u16*)smem;              // [256 ih][64 k] swizzled granules, 32KB
  u16* Bs = (u16*)(smem + 32768);    // [128 jk][64 k] swizzled granules, 16KB
  u16* Gs = (u16*)smem;              // [32 rij][1024 hk] swizzled, 64KB (after stage A)

  const int tid = threadIdx.x, lane = tid & 63, wv = tid >> 6;
  const int l15 = lane & 15, quad = lane >> 4;
  const int wm = wv >> 1, wn = wv & 1;
  const int jT = blockIdx.x, iT = blockIdx.y;

  const u16* gA = a_t + iT * 256 * SDIM;
  const u16* gB = b_t + jT * 128 * SDIM;

  const f32x4 fz = {0.f, 0.f, 0.f, 0.f};
  f32x4 acc[4][8];                   // [jt][it]
  #pragma unroll
  for (int jt = 0; jt < 4; ++jt)
    #pragma unroll
    for (int it = 0; it < 8; ++it) acc[jt][it] = fz;

  for (int ch = 0; ch < 2; ++ch) {
    __syncthreads();
    #pragma unroll
    for (int it = 0; it < 8; ++it) {             // As: 2048 granules
      const int f = it * 256 + tid;
      const int row = f >> 3, g = f & 7;
      *(short8*)&As[row * 64 + ((g ^ (row & 7)) << 3)] =
          *(const short8*)&gA[row * SDIM + ch * 64 + (g << 3)];
    }
    #pragma unroll
    for (int it = 0; it < 4; ++it) {             // Bs: 1024 granules
      const int f = it * 256 + tid;
      const int row = f >> 3, g = f & 7;
      *(short8*)&Bs[row * 64 + ((g ^ (row & 7)) << 3)] =
          *(const short8*)&gB[row * SDIM + ch * 64 + (g << 3)];
    }
    __syncthreads();
    #pragma unroll
    for (int ks = 0; ks < 2; ++ks) {
      const int g = ks * 4 + quad;
      short8 af[8], bf[4];
      #pragma unroll
      for (int it = 0; it < 8; ++it) {
        const int row = wm * 128 + it * 16 + l15;
        af[it] = *(const short8*)&As[row * 64 + ((g ^ (row & 7)) << 3)];
      }
      #pragma unroll
      for (int jt = 0; jt < 4; ++jt) {
        const int row = wn * 64 + jt * 16 + l15;
        bf[jt] = *(const short8*)&Bs[row * 64 + ((g ^ (row & 7)) << 3)];
      }
      #pragma unroll
      for (int jt = 0; jt < 4; ++jt)
        #pragma unroll
        for (int it = 0; it < 8; ++it)
          acc[jt][it] = __builtin_amdgcn_mfma_f32_16x16x32_bf16(bf[jt], af[it], acc[jt][it], 0, 0, 0);
    }
  }
  __syncthreads();

  // Gs dump: D[m=jk (quad*4+r), n=ih (l15)]; 4 regs = 4 consecutive hk -> b64.
  #pragma unroll
  for (int jt = 0; jt < 4; ++jt)
    #pragma unroll
    for (int it = 0; it < 8; ++it) {
      const int rij = (wm * 4 + (it >> 1)) * 4 + (wn * 2 + (jt >> 1));
      const int ih31 = (it & 1) * 16 + l15;
      const int hk = ih31 * 32 + (jt & 1) * 16 + quad * 4;   // base of 4
      const int g4 = hk >> 2;
      const int g4s = g4 ^ ((g4 >> 4) & 6) ^ ((rij & 7) << 1);
      __hip_bfloat162 lo = __float22bfloat162_rn(float2{acc[jt][it][0], acc[jt][it][1]});
      __hip_bfloat162 hi = __float22bfloat162_rn(float2{acc[jt][it][2], acc[jt][it][3]});
      union { __hip_bfloat162 h[2]; uint2 u; } pk; pk.h[0] = lo; pk.h[1] = hi;
      *(uint2*)&Gs[rij * 1024 + (g4s << 2)] = pk.u;
    }
  __syncthreads();

  // Stage B: wave wv owns K-quarter kk in [wv*8, wv*8+8); all 4 p-tiles.
  f32x4 ob[2][4];
  #pragma unroll
  for (int rh = 0; rh < 2; ++rh)
    #pragma unroll
    for (int pt = 0; pt < 4; ++pt) ob[rh][pt] = fz;
  #pragma unroll 2
  for (int kq = 0; kq < 8; ++kq) {
    const int kk = wv * 8 + kq;
    const int g4e = kk * 8 + quad * 2;
    const int go = (g4e ^ ((g4e >> 4) & 6) ^ ((l15 & 7) << 1)) << 2;
    const short8 g0 = *(const short8*)&Gs[l15 * 1024 + go];
    const short8 g1 = *(const short8*)&Gs[(16 + l15) * 1024 + go];
    #pragma unroll
    for (int pt = 0; pt < 4; ++pt) {
      const short8 wf = *(const short8*)&W_t[(pt * 16 + l15) * 1024 + kk * 32 + quad * 8];
      ob[0][pt] = __builtin_amdgcn_mfma_f32_16x16x32_bf16(g0, wf, ob[0][pt], 0, 0, 0);
      ob[1][pt] = __builtin_amdgcn_mfma_f32_16x16x32_bf16(g1, wf, ob[1][pt], 0, 0, 0);
    }
  }
  __syncthreads();   // Gs reads done; reuse smem for partial exchange

  // partial exchange: slice (kh, pt) layout [psub 16][pitch 36], b128-friendly.
  float* red = (float*)smem;   // 16 slices x 576 f32 = 36 KB
  #pragma unroll
  for (int rh = 0; rh < 2; ++rh)
    #pragma unroll
    for (int pt = 0; pt < 4; ++pt)
      *(f32x4*)&red[(wv * 4 + pt) * 576 + l15 * 36 + rh * 16 + quad * 4] = ob[rh][pt];
  __syncthreads();
  f32x4 fin0 = fz, fin1 = fz;
  #pragma unroll
  for (int kh = 0; kh < 4; ++kh) {
    fin0 += *(const f32x4*)&red[(kh * 4 + wv) * 576 + l15 * 36 + quad * 4];
    fin1 += *(const f32x4*)&red[(kh * 4 + wv) * 576 + l15 * 36 + 16 + quad * 4];
  }

  const int p = wv * 16 + l15;
  const float bop = bo[p];
  #pragma unroll
  for (int r = 0; r < 4; ++r) {
    {
      const int rij = quad * 4 + r;
      const int iG = iT * 8 + (rij >> 2), jG = jT * 4 + (rij & 3);
      out[(iG * NDIM + jG) * PDIM + p] = fin0[r] + bop;
    }
    {
      const int rij = 16 + quad * 4 + r;
      const int iG = iT * 8 + (rij >> 2), jG = jT * 4 + (rij & 3);
      out[(iG * NDIM + jG) * PDIM + p] = fin1[r] + bop;
    }
  }
}

extern "C" void kernel_launch(void* const* d_in, const int* in_sizes, int n_in,
                              void* d_out, int out_size, void* d_ws, size_t ws_size,
                              hipStream_t stream) {
  const float* msa   = (const float*)d_in[0];
  const float* mask  = (const float*)d_in[1];
  const float* gamma = (const float*)d_in[2];
  const float* beta  = (const float*)d_in[3];
  const float* Wa    = (const float*)d_in[4];
  const float* ba    = (const float*)d_in[5];
  const float* Wb    = (const float*)d_in[6];
  const float* bb    = (const float*)d_in[7];
  const float* Wo    = (const float*)d_in[8];
  const float* bo    = (const float*)d_in[9];

  char* ws = (char*)d_ws;
  u16* a_t = (u16*)ws;                       // 2 MB: [8192 ih][128 s] bf16
  u16* b_t = (u16*)(ws + (2u << 20));        // 2 MB: [8192 jk][128 s] bf16
  u16* W_t = (u16*)(ws + (4u << 20));        // 128 KB: [64 p][1024 hk] bf16

  k_pre<<<dim3(512), dim3(256), 0, stream>>>(msa, mask, gamma, beta,
                                             Wa, ba, Wb, bb, Wo, a_t, b_t, W_t);
  k_fused<<<dim3(64, 32), dim3(256), 0, stream>>>(a_t, b_t, W_t, bo, (float*)d_out);
}